// Round 17
// baseline (905.863 us; speedup 1.0000x reference)
//
#include <hip/hip_runtime.h>

#define N_NODES 50000
#define N_EDGES 200000
#define N_TRAIN 100000
#define DIM     512
#define NCLS    7
#define NSB     ((N_NODES + 255) / 256)   // scan blocks = 196

// GEMM1 row-thirds (multiples of 128)
#define M1A 16768
#define M1B 16640
#define M1C (N_NODES - M1A - M1B)   // 16592

typedef unsigned short ushort;
typedef _Float16 f16x8 __attribute__((ext_vector_type(8)));
typedef float    f32x4 __attribute__((ext_vector_type(4)));

// ---------- f16 helpers ----------
__device__ __forceinline__ ushort f2h(float f) {
    _Float16 h = (_Float16)f;
    union { _Float16 h; ushort u; } v; v.h = h; return v.u;
}
__device__ __forceinline__ float h2f(ushort u) {
    union { ushort u; _Float16 h; } v; v.u = u; return (float)v.h;
}

__device__ __forceinline__ void gload_lds16(const void* g, void* l) {
    __builtin_amdgcn_global_load_lds((const __attribute__((address_space(1))) unsigned int*)g,
                                     (__attribute__((address_space(3))) unsigned int*)l,
                                     16, 0, 0);
}

#define VMWAIT(N) asm volatile("s_waitcnt vmcnt(" #N ")" ::: "memory")
#define LGKM0()   asm volatile("s_waitcnt lgkmcnt(0)" ::: "memory")
#define BAR() do { asm volatile("" ::: "memory"); __builtin_amdgcn_s_barrier(); \
                   asm volatile("" ::: "memory"); } while (0)

// ---------------- small utility kernels ----------------

__global__ void zero_kernel(float* p, int n) {
    int i = blockIdx.x * blockDim.x + threadIdx.x;
    if (i < n) p[i] = 0.0f;
}

// ---------------- CSR build (by dst) ----------------

__global__ void hist_kernel(const int* __restrict__ ei, int* __restrict__ cnt) {
    int e = blockIdx.x * blockDim.x + threadIdx.x;
    if (e < N_EDGES) atomicAdd(&cnt[ei[N_EDGES + e]], 1);
}

__global__ __launch_bounds__(256) void scan1_kernel(const int* __restrict__ cnt,
                                                    int* __restrict__ off,
                                                    int* __restrict__ bsum) {
    __shared__ int s[256];
    int t = threadIdx.x, b = blockIdx.x;
    int i = b * 256 + t;
    s[t] = (i < N_NODES) ? cnt[i] : 0;
    __syncthreads();
    for (int d = 1; d < 256; d <<= 1) {
        int add = (t >= d) ? s[t - d] : 0;
        __syncthreads();
        s[t] += add;
        __syncthreads();
    }
    if (i < N_NODES) off[i + 1] = s[t];
    if (t == 255) bsum[b] = s[255];
}

__global__ __launch_bounds__(256) void scan2_kernel(int* bsum) {
    __shared__ int s[256];
    int t = threadIdx.x;
    s[t] = (t < NSB) ? bsum[t] : 0;
    __syncthreads();
    for (int d = 1; d < 256; d <<= 1) {
        int add = (t >= d) ? s[t - d] : 0;
        __syncthreads();
        s[t] += add;
        __syncthreads();
    }
    if (t < NSB) bsum[t] = s[t];
}

__global__ __launch_bounds__(256) void scan3_kernel(int* off, const int* __restrict__ bsum) {
    int t = threadIdx.x, b = blockIdx.x;
    int i = b * 256 + t;
    if (i == 0) off[0] = 0;
    if (i < N_NODES) off[i + 1] += (b > 0 ? bsum[b - 1] : 0);
}

__global__ void fillprep_kernel(const int* __restrict__ off, int* __restrict__ wcur) {
    int i = blockIdx.x * blockDim.x + threadIdx.x;
    if (i < N_NODES) wcur[i] = off[i];
}

__global__ void fill_kernel(const int* __restrict__ ei, int* __restrict__ wcur,
                            int* __restrict__ srclist) {
    int e = blockIdx.x * blockDim.x + threadIdx.x;
    if (e < N_EDGES) {
        int d = ei[N_EDGES + e];
        int pos = atomicAdd(&wcur[d], 1);
        srclist[pos] = ei[e];
    }
}

// ---- aggregation (fp32 in): out[n] = scale*base[n] + sum feat[src], f16 out ----

__global__ __launch_bounds__(128) void gather_h_kernel(const float* __restrict__ feat,
                                                       const float* __restrict__ base,
                                                       const float* eps_or_null,
                                                       const int* __restrict__ off,
                                                       const int* __restrict__ srclist,
                                                       ushort* __restrict__ oh) {
    int n = blockIdx.x;
    int t = threadIdx.x;
    float s = 1.0f;
    if (eps_or_null) s = 1.0f + *eps_or_null;
    int e0 = off[n], e1 = off[n + 1];
    float4 acc = ((const float4*)(base + (size_t)n * DIM))[t];
    acc.x *= s; acc.y *= s; acc.z *= s; acc.w *= s;
    for (int e = e0; e < e1; ++e) {
        int srcn = srclist[e];
        float4 v = ((const float4*)(feat + (size_t)srcn * DIM))[t];
        acc.x += v.x; acc.y += v.y; acc.z += v.z; acc.w += v.w;
    }
    size_t o = (size_t)n * DIM + t * 4;
    ushort4 r;
    r.x = f2h(acc.x); r.y = f2h(acc.y); r.z = f2h(acc.z); r.w = f2h(acc.w);
    *(ushort4*)(oh + o) = r;
}

// ---- aggregation (f16 in): out[n] = scale*base[n] + sum feat[src], f16 out ----

__global__ __launch_bounds__(128) void gather_h16_kernel(const ushort* __restrict__ feat,
                                                         const ushort* __restrict__ base,
                                                         const float* eps_or_null,
                                                         const int* __restrict__ off,
                                                         const int* __restrict__ srclist,
                                                         ushort* __restrict__ oh) {
    int n = blockIdx.x;
    int t = threadIdx.x;
    float s = 1.0f;
    if (eps_or_null) s = 1.0f + *eps_or_null;
    int e0 = off[n], e1 = off[n + 1];
    ushort4 b4 = ((const ushort4*)(base + (size_t)n * DIM))[t];
    float4 acc;
    acc.x = h2f(b4.x) * s; acc.y = h2f(b4.y) * s;
    acc.z = h2f(b4.z) * s; acc.w = h2f(b4.w) * s;
    for (int e = e0; e < e1; ++e) {
        int srcn = srclist[e];
        ushort4 v = ((const ushort4*)(feat + (size_t)srcn * DIM))[t];
        acc.x += h2f(v.x); acc.y += h2f(v.y); acc.z += h2f(v.z); acc.w += h2f(v.w);
    }
    size_t o = (size_t)n * DIM + t * 4;
    ushort4 r;
    r.x = f2h(acc.x); r.y = f2h(acc.y); r.z = f2h(acc.z); r.w = f2h(acc.w);
    *(ushort4*)(oh + o) = r;
}

// ---- fp32 -> f16 (for x) ----
__global__ void convert_h_kernel(const float* __restrict__ X,
                                 ushort* __restrict__ oh, size_t n4) {
    size_t i = (size_t)blockIdx.x * blockDim.x + threadIdx.x;
    size_t stride = (size_t)gridDim.x * blockDim.x;
    const float4* X4 = (const float4*)X;
    for (; i < n4; i += stride) {
        float4 v = X4[i];
        ushort4 r;
        r.x = f2h(v.x); r.y = f2h(v.y); r.z = f2h(v.z); r.w = f2h(v.w);
        *(ushort4*)(oh + i * 4) = r;
    }
}

// ---- all 6 W (K x N fp32) -> transposed single f16 [N][K], packed in wt ----
__global__ void wconvert6_kernel(const float* __restrict__ W0, const float* __restrict__ W1,
                                 const float* __restrict__ W2, const float* __restrict__ W3,
                                 const float* __restrict__ W4, const float* __restrict__ W5,
                                 ushort* __restrict__ wt) {
    int p = blockIdx.y;
    const float* W = (p == 0) ? W0 : (p == 1) ? W1 : (p == 2) ? W2
                   : (p == 3) ? W3 : (p == 4) ? W4 : W5;
    ushort* Th = wt + (size_t)p * 262144;
    int idx = blockIdx.x * 256 + threadIdx.x;   // over 512*512
    int n = idx >> 9, k = idx & 511;
    Th[idx] = f2h(W[k * DIM + n]);
}

// ---- BN2 fold: lw1s[n][k] = f16(lin1_W[k][n] * scale[k]) ----
__global__ void wfold_kernel(const float* __restrict__ W1, const float* __restrict__ st2,
                             ushort* __restrict__ lw1s) {
    int idx = blockIdx.x * 256 + threadIdx.x;
    int n = idx >> 9, k = idx & 511;
    lw1s[idx] = f2h(W1[k * DIM + n] * st2[1024 + k]);
}

// ---- BN2 bias fold: b1f[c] = lin1_b[c] + sum_k shift[k]*lin1_W[k][c] ----
__global__ void bfold_kernel(const float* __restrict__ W1, const float* __restrict__ b1,
                             const float* __restrict__ st2, float* __restrict__ b1f) {
    int c = threadIdx.x;   // 512 threads, one block
    float s = 0.f;
#pragma unroll 8
    for (int k = 0; k < DIM; k++) s += st2[1536 + k] * W1[k * DIM + c];
    b1f[c] = b1[c] + s;
}

// --------- MFMA GEMM: single-pass f16, 128x128 tile, 8 waves, 3x16KB counted-vmcnt ---------
// r14 GEMM body (best of 8 structural variants). DUAL dispatch: blockIdx.y selects param
// set; per-set M with block-uniform early-exit (before any barrier) so a partial-size
// set-1 GEMM (e.g. a GEMM1 row-third) co-runs with a full set-0 GEMM. r16 measured dual
// co-residency at 70.5us/GEMM vs 111 solo (independent streams fill each other's stalls).

__global__ __launch_bounds__(512, 6) void gemm_f16_kernel(
    const ushort* __restrict__ Ahp0, const ushort* __restrict__ Wf0,
    const float* __restrict__ bias0, const float* __restrict__ amf0,
    const ushort* __restrict__ amh0, const float* __restrict__ bnst0,
    float* __restrict__ Cf0, ushort* __restrict__ Oh0, float* __restrict__ stats0,
    int relu0, int mode0, int M0,
    const ushort* __restrict__ Ahp1, const ushort* __restrict__ Wf1,
    const float* __restrict__ bias1, const float* __restrict__ amf1,
    const ushort* __restrict__ amh1, const float* __restrict__ bnst1,
    float* __restrict__ Cf1, ushort* __restrict__ Oh1, float* __restrict__ stats1,
    int relu1, int mode1, int M1)
{
    __shared__ __align__(16) char smem[3 * 16384];   // 48KB

    // select param set (block-uniform)
    const ushort* Ahp; const ushort* Wf; const float* bias; const float* addmat_f;
    const ushort* addmat_h; const float* bnst; float* Cf; ushort* Oh; float* stats;
    int relu, mode, M;
    if (blockIdx.y == 0) {
        Ahp = Ahp0; Wf = Wf0; bias = bias0; addmat_f = amf0; addmat_h = amh0;
        bnst = bnst0; Cf = Cf0; Oh = Oh0; stats = stats0;
        relu = relu0; mode = mode0; M = M0;
    } else {
        Ahp = Ahp1; Wf = Wf1; bias = bias1; addmat_f = amf1; addmat_h = amh1;
        bnst = bnst1; Cf = Cf1; Oh = Oh1; stats = stats1;
        relu = relu1; mode = mode1; M = M1;
    }

    int tid = threadIdx.x;
    int w = tid >> 6;       // wave 0..7
    int l = tid & 63;
    int wm = w >> 2;        // 0..1  (64-row group)
    int wn = w & 3;         // 0..3  (32-col group)

    // bijective XCD chunk swizzle, bn fastest
    int nwg = gridDim.x;
    int q = nwg >> 3, r = nwg & 7;
    int xcd = blockIdx.x & 7, idx = blockIdx.x >> 3;
    int wgid = (xcd < r ? xcd * (q + 1) : r * (q + 1) + (xcd - r) * q) + idx;
    int bm = (wgid >> 2) * 128;
    int bn = (wgid & 3) * 128;

    if (bm >= M) return;    // block-uniform early exit (partial set-1 GEMMs); before barriers

    f32x4 acc[4][2];
#pragma unroll
    for (int i = 0; i < 4; i++)
#pragma unroll
        for (int j = 0; j < 2; j++) acc[i][j] = (f32x4){0.f, 0.f, 0.f, 0.f};

    int ro = l & 15;
    int co = l >> 4;

    size_t soff[2]; int lofs[2];
#pragma unroll
    for (int t2 = 0; t2 < 2; t2++) {
        int c = 2 * w + t2;
        int row0, base_; bool cl;
        if (c < 8) { row0 = c * 16;       base_ = bm; cl = true;  lofs[t2] = c * 1024; }
        else       { row0 = (c - 8) * 16; base_ = bn; cl = false; lofs[t2] = 8192 + (c - 8) * 1024; }
        int lrit = row0 + (l >> 2);
        int rr = base_ + lrit;
        if (cl) rr = min(rr, M - 1);
        int kc = (l & 3) ^ ((lrit >> 1) & 3);
        soff[t2] = (size_t)rr * DIM + kc * 8;
    }
    const ushort* sp0 = (2 * w < 8) ? Ahp : Wf;
    const ushort* sp1 = (2 * w + 1 < 8) ? Ahp : Wf;

    int aoff[4], woff[2];
#pragma unroll
    for (int i = 0; i < 4; i++) {
        int arow = wm * 64 + i * 16 + ro;
        aoff[i] = arow * 64 + ((co ^ ((arow >> 1) & 3)) << 4);
    }
#pragma unroll
    for (int j = 0; j < 2; j++) {
        int wrow = wn * 32 + j * 16 + ro;
        woff[j] = 8192 + wrow * 64 + ((co ^ ((wrow >> 1) & 3)) << 4);
    }

#define STAGE(BB, K0) do {                                                        \
    char* sb_ = smem + (BB) * 16384;                                              \
    gload_lds16(sp0 + soff[0] + (K0), sb_ + lofs[0]);                             \
    gload_lds16(sp1 + soff[1] + (K0), sb_ + lofs[1]);                             \
} while (0)

#define COMPUTE(BB) do {                                                          \
    const char* bb_ = (const char*)smem + (BB) * 16384;                           \
    f16x8 fa[4], fw2[2];                                                          \
    _Pragma("unroll")                                                             \
    for (int i = 0; i < 4; i++) fa[i] = *(const f16x8*)(bb_ + aoff[i]);           \
    _Pragma("unroll")                                                             \
    for (int j = 0; j < 2; j++) fw2[j] = *(const f16x8*)(bb_ + woff[j]);          \
    __builtin_amdgcn_s_setprio(1);                                                \
    _Pragma("unroll")                                                             \
    for (int i = 0; i < 4; i++)                                                   \
        _Pragma("unroll")                                                         \
        for (int j = 0; j < 2; j++)                                               \
            acc[i][j] = __builtin_amdgcn_mfma_f32_16x16x32_f16(fa[i], fw2[j], acc[i][j], 0, 0, 0); \
    __builtin_amdgcn_s_setprio(0);                                                \
} while (0)

    STAGE(0, 0);
    STAGE(1, 32);
    STAGE(2, 64);

    int bufi = 0;
    for (int ks = 0; ks < 16; ks++) {
        if (ks < 14)      { VMWAIT(4); }
        else if (ks == 14){ VMWAIT(2); }
        else              { VMWAIT(0); }
        BAR();
        COMPUTE(bufi);
        LGKM0();
        BAR();
        if (ks <= 12) STAGE(bufi, (ks + 3) * 32);
        bufi = (bufi == 2) ? 0 : bufi + 1;
    }

#undef STAGE
#undef COMPUTE

    // epilogue: C/D layout col=lane&15, row=(lane>>4)*4+reg
    int colbase = bn + wn * 32 + ro;
    int rowbase = bm + wm * 64 + co * 4;
    float sacc[2] = {0.f, 0.f};
    float qacc[2] = {0.f, 0.f};
#pragma unroll
    for (int j = 0; j < 2; j++) {
        int col = colbase + j * 16;
        float bi = bias ? bias[col] : 0.f;
        float sc = 0.f, sh = 0.f;
        if (bnst) { sc = bnst[1024 + col]; sh = bnst[1536 + col]; }
#pragma unroll
        for (int i = 0; i < 4; i++) {
#pragma unroll
            for (int rg = 0; rg < 4; rg++) {
                int row = rowbase + i * 16 + rg;
                if (row < M) {
                    float v = acc[i][j][rg] + bi;
                    if (addmat_f || addmat_h) {
                        float am = addmat_f ? addmat_f[(size_t)row * DIM + col]
                                            : h2f(addmat_h[(size_t)row * DIM + col]);
                        if (bnst) am = fmaxf(am * sc + sh, 0.f);
                        v += am;
                    }
                    if (relu) v = fmaxf(v, 0.f);
                    if (mode == 0) Cf[(size_t)row * DIM + col] = v;
                    else           Oh[(size_t)row * DIM + col] = f2h(v);
                    if (stats) { sacc[j] += v; qacc[j] += v * v; }
                }
            }
        }
    }
    if (stats) {
#pragma unroll
        for (int j = 0; j < 2; j++) {
            float ss = sacc[j], qq = qacc[j];
            ss += __shfl_xor(ss, 16); qq += __shfl_xor(qq, 16);
            ss += __shfl_xor(ss, 32); qq += __shfl_xor(qq, 32);
            if (co == 0) {
                int col = colbase + j * 16;
                atomicAdd(&stats[col], ss);
                atomicAdd(&stats[DIM + col], qq);
            }
        }
    }
}

// ---------------- batch norm finalize ----------------

__global__ void bn_finalize_kernel(float* st, const float* __restrict__ g,
                                   const float* __restrict__ b, int M) {
    int c = threadIdx.x;  // 512 threads
    float mean = st[c] / (float)M;
    float var = st[DIM + c] / (float)M - mean * mean;
    float sc = g[c] * rsqrtf(var + 1e-5f);
    st[1024 + c] = sc;
    st[1536 + c] = b[c] - mean * sc;
}

// ---------------- final pair gather + (T,512)@(512,7), f16 H ----------------

__global__ __launch_bounds__(256) void pair_kernel(const ushort* __restrict__ H,
                                                   const int* __restrict__ ei,
                                                   const int* __restrict__ teid,
                                                   const float* __restrict__ W,  // 512x7
                                                   const float* __restrict__ bias,
                                                   float* __restrict__ out) {
    int lane = threadIdx.x & 63;
    int wid = blockIdx.x * 4 + (threadIdx.x >> 6);
    int nw = gridDim.x * 4;
    int d0 = lane * 8;

    float wreg[8][NCLS];
#pragma unroll
    for (int qd = 0; qd < 8; qd++)
#pragma unroll
        for (int c = 0; c < NCLS; c++)
            wreg[qd][c] = W[(d0 + qd) * NCLS + c];
    float bi[NCLS];
#pragma unroll
    for (int c = 0; c < NCLS; c++) bi[c] = bias[c];

    for (int t = wid; t < N_TRAIN; t += nw) {
        int id = teid[t];
        int n0 = ei[id];
        int n1 = ei[N_EDGES + id];
        f16x8 av = *(const f16x8*)(H + (size_t)n0 * DIM + d0);
        f16x8 bv = *(const f16x8*)(H + (size_t)n1 * DIM + d0);
        float acc[NCLS];
#pragma unroll
        for (int c = 0; c < NCLS; c++) acc[c] = 0.f;
#pragma unroll
        for (int qd = 0; qd < 8; qd++) {
            float p = (float)av[qd] * (float)bv[qd];
#pragma unroll
            for (int c = 0; c < NCLS; c++) acc[c] += p * wreg[qd][c];
        }
#pragma unroll
        for (int off = 32; off; off >>= 1)
#pragma unroll
            for (int c = 0; c < NCLS; c++) acc[c] += __shfl_down(acc[c], off);
        if (lane == 0) {
#pragma unroll
            for (int c = 0; c < NCLS; c++) out[(size_t)t * NCLS + c] = acc[c] + bi[c];
        }
    }
}

// ---------------- launch ----------------

extern "C" void kernel_launch(void* const* d_in, const int* in_sizes, int n_in,
                              void* d_out, int out_size, void* d_ws, size_t ws_size,
                              hipStream_t stream) {
    const float* x      = (const float*)d_in[0];
    const float* graph  = (const float*)d_in[1];
    const int*   ei     = (const int*)d_in[2];
    const int*   teid   = (const int*)d_in[3];
    const float* W_sub  = (const float*)d_in[4];
    const float* bn1_g  = (const float*)d_in[5];
    const float* bn1_b  = (const float*)d_in[6];
    const float* fcx_W  = (const float*)d_in[7];
    const float* fcx_b  = (const float*)d_in[8];
    const float* eps1   = (const float*)d_in[9];
    const float* g_W1   = (const float*)d_in[10];
    const float* g_b1   = (const float*)d_in[11];
    const float* g_W2   = (const float*)d_in[12];
    const float* g_b2   = (const float*)d_in[13];
    const float* gbn_g  = (const float*)d_in[14];
    const float* gbn_b  = (const float*)d_in[15];
    const float* lin1_W = (const float*)d_in[16];
    const float* lin1_b = (const float*)d_in[17];
    const float* lin2_W = (const float*)d_in[18];
    const float* lin2_b = (const float*)d_in[19];
    const float* fc2_W  = (const float*)d_in[20];
    const float* fc2_b  = (const float*)d_in[21];
    float* out = (float*)d_out;

    char* ws = (char*)d_ws;
    size_t NB = (size_t)N_NODES * DIM * sizeof(float);    // 102.4 MB per slot
    float* slotA = (float*)(ws);
    float* slotB = (float*)(ws + NB);
    float* slotC = (float*)(ws + 2 * NB);
    float* st1   = (float*)(ws + 3 * NB);                 // 2048 floats
    float* st2   = st1 + 2048;
    int* off     = (int*)(st2 + 2048);
    int* wcur    = off + (N_NODES + 1);
    int* srclist = wcur + N_NODES;
    int* bsum    = srclist + N_EDGES;
    ushort* wt   = (ushort*)(bsum + 256);                 // 6 W^T f16, 0.5MB each
    ushort* Wsub_f = wt;
    ushort* fcx_f  = wt + 1 * 262144;
    ushort* gw1_f  = wt + 2 * 262144;
    ushort* gw2_f  = wt + 3 * 262144;
    ushort* lw2_f  = wt + 5 * 262144;
    ushort* lw1s   = wt + 6 * 262144;   // BN2-folded lin1 W^T
    float*  b1f    = (float*)(lw1s + 262144);   // BN2-folded lin1 bias (512)

    // f16 buffer map (each fp32 slot = two 51.2MB f16 buffers):
    //  A_h  = graph-agg (live until last GEMM1 third)    slotA.0
    //  X_h  = f16(x), free after GEMM2                   slotA.1 -> reused as G4 out (A2_h)
    //  B_h  = sub_x_raw (GEMM1 thirds out)               slotB.0
    //  B2_h = G3 out                                     slotB.1
    //  C2_h = G2 out, free after gather16 -> G5 out      slotC.0
    //  AG_h = x-agg, free after G3 -> H_h (G6 out)       slotC.1
    size_t HN = (size_t)N_NODES * DIM;
    ushort* A_h  = (ushort*)slotA;       ushort* X_h  = A_h + HN;   ushort* A2_h = X_h;
    ushort* B_h  = (ushort*)slotB;       ushort* B2_h = B_h + HN;
    ushort* C2_h = (ushort*)slotC;       ushort* AG_h = C2_h + HN;  ushort* H_h  = AG_h;

    size_t n4 = HN / 4;
    int mt = (N_NODES + 127) / 128;            // 391 row tiles
    dim3 ggrid(mt * 4);                        // 1564 blocks (single GEMM)
    dim3 gdual(mt * 4, 2);                     // dual dispatch

    const ushort* G1A[3] = { A_h, A_h + (size_t)M1A * DIM, A_h + (size_t)(M1A + M1B) * DIM };
    const float*  G1G[3] = { graph, graph + (size_t)M1A * DIM, graph + (size_t)(M1A + M1B) * DIM };
    ushort*       G1O[3] = { B_h, B_h + (size_t)M1A * DIM, B_h + (size_t)(M1A + M1B) * DIM };
    const int     G1M[3] = { M1A, M1B, M1C };

#define NULLSET \
    (const ushort*)nullptr, (const ushort*)nullptr, (const float*)nullptr, \
    (const float*)nullptr, (const ushort*)nullptr, (const float*)nullptr, \
    (float*)nullptr, (ushort*)nullptr, (float*)nullptr, 0, 0, 0

    zero_kernel<<<16, 256, 0, stream>>>(st1, 4096);
    zero_kernel<<<NSB, 256, 0, stream>>>((float*)wcur, N_NODES);

    // CSR by dst
    hist_kernel<<<(N_EDGES + 255) / 256, 256, 0, stream>>>(ei, wcur);
    scan1_kernel<<<NSB, 256, 0, stream>>>(wcur, off, bsum);
    scan2_kernel<<<1, 256, 0, stream>>>(bsum);
    scan3_kernel<<<NSB, 256, 0, stream>>>(off, bsum);
    fillprep_kernel<<<NSB, 256, 0, stream>>>(off, wcur);
    fill_kernel<<<(N_EDGES + 255) / 256, 256, 0, stream>>>(ei, wcur, srclist);

    // W^T f16 conversions; x -> f16; graph-agg -> A_h
    wconvert6_kernel<<<dim3(1024, 6), 256, 0, stream>>>(W_sub, fcx_W, g_W1, g_W2, lin1_W, lin2_W, wt);
    convert_h_kernel<<<2048, 256, 0, stream>>>(x, X_h, n4);
    gather_h_kernel<<<N_NODES, 128, 0, stream>>>(graph, graph, nullptr, off, srclist, A_h);

    // GEMM2 (solo): h = f16(x) @ fcx_f + fcx_b -> C2_h
    gemm_f16_kernel<<<ggrid, 512, 0, stream>>>(
        X_h, fcx_f, fcx_b, (const float*)nullptr, (const ushort*)nullptr,
        (const float*)nullptr, (float*)nullptr, C2_h, (float*)nullptr, 0, 1, N_NODES,
        NULLSET);

    // agg = (1+eps)*h + gather(h) -> AG_h
    gather_h16_kernel<<<N_NODES, 128, 0, stream>>>(C2_h, C2_h, eps1, off, srclist, AG_h);

    // DUAL A: G3 full || G1 third 0
    gemm_f16_kernel<<<gdual, 512, 0, stream>>>(
        AG_h, gw1_f, g_b1, (const float*)nullptr, (const ushort*)nullptr,
        (const float*)nullptr, (float*)nullptr, B2_h, (float*)nullptr, 1, 1, N_NODES,
        G1A[0], Wsub_f, (const float*)nullptr, G1G[0], (const ushort*)nullptr,
        (const float*)nullptr, (float*)nullptr, G1O[0], st1, 0, 1, G1M[0]);

    // DUAL B: G4 full (stats st2) || G1 third 1
    gemm_f16_kernel<<<gdual, 512, 0, stream>>>(
        B2_h, gw2_f, g_b2, (const float*)nullptr, (const ushort*)nullptr,
        (const float*)nullptr, (float*)nullptr, A2_h, st2, 1, 1, N_NODES,
        G1A[1], Wsub_f, (const float*)nullptr, G1G[1], (const ushort*)nullptr,
        (const float*)nullptr, (float*)nullptr, G1O[1], st1, 0, 1, G1M[1]);

    bn_finalize_kernel<<<1, 512, 0, stream>>>(st2, gbn_g, gbn_b, N_NODES);
    // BN2 fold into lin1: W1' = diag(sc)W1 (f16), b1' = b1 + sh@W1
    wfold_kernel<<<1024, 256, 0, stream>>>(lin1_W, st2, lw1s);
    bfold_kernel<<<1, 512, 0, stream>>>(lin1_W, lin1_b, st2, b1f);

    // DUAL C: G5 full || G1 third 2
    gemm_f16_kernel<<<gdual, 512, 0, stream>>>(
        A2_h, lw1s, b1f, (const float*)nullptr, (const ushort*)nullptr,
        (const float*)nullptr, (float*)nullptr, C2_h, (float*)nullptr, 1, 1, N_NODES,
        G1A[2], Wsub_f, (const float*)nullptr, G1G[2], (const ushort*)nullptr,
        (const float*)nullptr, (float*)nullptr, G1O[2], st1, 0, 1, G1M[2]);

    // st1 complete only now
    bn_finalize_kernel<<<1, 512, 0, stream>>>(st1, bn1_g, bn1_b, N_NODES);

    // GEMM6 (solo): H = h @ lin2_W + lin2_b + relu(bn1(sub_x_raw)) -> H_h
    gemm_f16_kernel<<<ggrid, 512, 0, stream>>>(
        C2_h, lw2_f, lin2_b, (const float*)nullptr, B_h,
        st1, (float*)nullptr, H_h, (float*)nullptr, 0, 1, N_NODES,
        NULLSET);

    // out = (H[n0]*H[n1]) @ fc2_W + fc2_b
    pair_kernel<<<2048, 256, 0, stream>>>(H_h, ei, teid, fc2_W, fc2_b, out);

#undef NULLSET
}

// Round 18
// 688.442 us; speedup vs baseline: 1.3158x; 1.3158x over previous
//
#include <hip/hip_runtime.h>

#define N_NODES 50000
#define N_EDGES 200000
#define N_TRAIN 100000
#define DIM     512
#define NCLS    7
#define NSB     ((N_NODES + 255) / 256)   // scan blocks = 196

typedef unsigned short ushort;
typedef _Float16 f16x8 __attribute__((ext_vector_type(8)));
typedef float    f32x4 __attribute__((ext_vector_type(4)));

// ---------- f16 helpers ----------
__device__ __forceinline__ ushort f2h(float f) {
    _Float16 h = (_Float16)f;
    union { _Float16 h; ushort u; } v; v.h = h; return v.u;
}
__device__ __forceinline__ float h2f(ushort u) {
    union { ushort u; _Float16 h; } v; v.u = u; return (float)v.h;
}

__device__ __forceinline__ void gload_lds16(const void* g, void* l) {
    __builtin_amdgcn_global_load_lds((const __attribute__((address_space(1))) unsigned int*)g,
                                     (__attribute__((address_space(3))) unsigned int*)l,
                                     16, 0, 0);
}

#define VMWAIT(N) asm volatile("s_waitcnt vmcnt(" #N ")" ::: "memory")
#define LGKM0()   asm volatile("s_waitcnt lgkmcnt(0)" ::: "memory")
#define BAR() do { asm volatile("" ::: "memory"); __builtin_amdgcn_s_barrier(); \
                   asm volatile("" ::: "memory"); } while (0)

// ---------------- small utility kernels ----------------

__global__ void zero_kernel(float* p, int n) {
    int i = blockIdx.x * blockDim.x + threadIdx.x;
    if (i < n) p[i] = 0.0f;
}

// ---------------- CSR build (by dst) ----------------

__global__ void hist_kernel(const int* __restrict__ ei, int* __restrict__ cnt) {
    int e = blockIdx.x * blockDim.x + threadIdx.x;
    if (e < N_EDGES) atomicAdd(&cnt[ei[N_EDGES + e]], 1);
}

__global__ __launch_bounds__(256) void scan1_kernel(const int* __restrict__ cnt,
                                                    int* __restrict__ off,
                                                    int* __restrict__ bsum) {
    __shared__ int s[256];
    int t = threadIdx.x, b = blockIdx.x;
    int i = b * 256 + t;
    s[t] = (i < N_NODES) ? cnt[i] : 0;
    __syncthreads();
    for (int d = 1; d < 256; d <<= 1) {
        int add = (t >= d) ? s[t - d] : 0;
        __syncthreads();
        s[t] += add;
        __syncthreads();
    }
    if (i < N_NODES) off[i + 1] = s[t];
    if (t == 255) bsum[b] = s[255];
}

__global__ __launch_bounds__(256) void scan2_kernel(int* bsum) {
    __shared__ int s[256];
    int t = threadIdx.x;
    s[t] = (t < NSB) ? bsum[t] : 0;
    __syncthreads();
    for (int d = 1; d < 256; d <<= 1) {
        int add = (t >= d) ? s[t - d] : 0;
        __syncthreads();
        s[t] += add;
        __syncthreads();
    }
    if (t < NSB) bsum[t] = s[t];
}

__global__ __launch_bounds__(256) void scan3_kernel(int* off, const int* __restrict__ bsum) {
    int t = threadIdx.x, b = blockIdx.x;
    int i = b * 256 + t;
    if (i == 0) off[0] = 0;
    if (i < N_NODES) off[i + 1] += (b > 0 ? bsum[b - 1] : 0);
}

__global__ void fillprep_kernel(const int* __restrict__ off, int* __restrict__ wcur) {
    int i = blockIdx.x * blockDim.x + threadIdx.x;
    if (i < N_NODES) wcur[i] = off[i];
}

__global__ void fill_kernel(const int* __restrict__ ei, int* __restrict__ wcur,
                            int* __restrict__ srclist) {
    int e = blockIdx.x * blockDim.x + threadIdx.x;
    if (e < N_EDGES) {
        int d = ei[N_EDGES + e];
        int pos = atomicAdd(&wcur[d], 1);
        srclist[pos] = ei[e];
    }
}

// ---- aggregation (fp32 in): out[n] = scale*base[n] + sum feat[src], f16 out ----

__global__ __launch_bounds__(128) void gather_h_kernel(const float* __restrict__ feat,
                                                       const float* __restrict__ base,
                                                       const float* eps_or_null,
                                                       const int* __restrict__ off,
                                                       const int* __restrict__ srclist,
                                                       ushort* __restrict__ oh) {
    int n = blockIdx.x;
    int t = threadIdx.x;
    float s = 1.0f;
    if (eps_or_null) s = 1.0f + *eps_or_null;
    int e0 = off[n], e1 = off[n + 1];
    float4 acc = ((const float4*)(base + (size_t)n * DIM))[t];
    acc.x *= s; acc.y *= s; acc.z *= s; acc.w *= s;
    for (int e = e0; e < e1; ++e) {
        int srcn = srclist[e];
        float4 v = ((const float4*)(feat + (size_t)srcn * DIM))[t];
        acc.x += v.x; acc.y += v.y; acc.z += v.z; acc.w += v.w;
    }
    size_t o = (size_t)n * DIM + t * 4;
    ushort4 r;
    r.x = f2h(acc.x); r.y = f2h(acc.y); r.z = f2h(acc.z); r.w = f2h(acc.w);
    *(ushort4*)(oh + o) = r;
}

// ---- aggregation (f16 in): out[n] = scale*base[n] + sum feat[src], f16 out ----

__global__ __launch_bounds__(128) void gather_h16_kernel(const ushort* __restrict__ feat,
                                                         const ushort* __restrict__ base,
                                                         const float* eps_or_null,
                                                         const int* __restrict__ off,
                                                         const int* __restrict__ srclist,
                                                         ushort* __restrict__ oh) {
    int n = blockIdx.x;
    int t = threadIdx.x;
    float s = 1.0f;
    if (eps_or_null) s = 1.0f + *eps_or_null;
    int e0 = off[n], e1 = off[n + 1];
    ushort4 b4 = ((const ushort4*)(base + (size_t)n * DIM))[t];
    float4 acc;
    acc.x = h2f(b4.x) * s; acc.y = h2f(b4.y) * s;
    acc.z = h2f(b4.z) * s; acc.w = h2f(b4.w) * s;
    for (int e = e0; e < e1; ++e) {
        int srcn = srclist[e];
        ushort4 v = ((const ushort4*)(feat + (size_t)srcn * DIM))[t];
        acc.x += h2f(v.x); acc.y += h2f(v.y); acc.z += h2f(v.z); acc.w += h2f(v.w);
    }
    size_t o = (size_t)n * DIM + t * 4;
    ushort4 r;
    r.x = f2h(acc.x); r.y = f2h(acc.y); r.z = f2h(acc.z); r.w = f2h(acc.w);
    *(ushort4*)(oh + o) = r;
}

// ---- fp32 -> f16 (for x) ----
__global__ void convert_h_kernel(const float* __restrict__ X,
                                 ushort* __restrict__ oh, size_t n4) {
    size_t i = (size_t)blockIdx.x * blockDim.x + threadIdx.x;
    size_t stride = (size_t)gridDim.x * blockDim.x;
    const float4* X4 = (const float4*)X;
    for (; i < n4; i += stride) {
        float4 v = X4[i];
        ushort4 r;
        r.x = f2h(v.x); r.y = f2h(v.y); r.z = f2h(v.z); r.w = f2h(v.w);
        *(ushort4*)(oh + i * 4) = r;
    }
}

// ---- all 6 W (K x N fp32) -> transposed single f16 [N][K], packed in wt ----
__global__ void wconvert6_kernel(const float* __restrict__ W0, const float* __restrict__ W1,
                                 const float* __restrict__ W2, const float* __restrict__ W3,
                                 const float* __restrict__ W4, const float* __restrict__ W5,
                                 ushort* __restrict__ wt) {
    int p = blockIdx.y;
    const float* W = (p == 0) ? W0 : (p == 1) ? W1 : (p == 2) ? W2
                   : (p == 3) ? W3 : (p == 4) ? W4 : W5;
    ushort* Th = wt + (size_t)p * 262144;
    int idx = blockIdx.x * 256 + threadIdx.x;   // over 512*512
    int n = idx >> 9, k = idx & 511;
    Th[idx] = f2h(W[k * DIM + n]);
}

// ---- BN2 fold: lw1s[n][k] = f16(lin1_W[k][n] * scale[k]) ----
__global__ void wfold_kernel(const float* __restrict__ W1, const float* __restrict__ st2,
                             ushort* __restrict__ lw1s) {
    int idx = blockIdx.x * 256 + threadIdx.x;
    int n = idx >> 9, k = idx & 511;
    lw1s[idx] = f2h(W1[k * DIM + n] * st2[1024 + k]);
}

// ---- BN2 bias fold: b1f[c] = lin1_b[c] + sum_k shift[k]*lin1_W[k][c] ----
__global__ void bfold_kernel(const float* __restrict__ W1, const float* __restrict__ b1,
                             const float* __restrict__ st2, float* __restrict__ b1f) {
    int c = threadIdx.x;   // 512 threads, one block
    float s = 0.f;
#pragma unroll 8
    for (int k = 0; k < DIM; k++) s += st2[1536 + k] * W1[k * DIM + c];
    b1f[c] = b1[c] + s;
}

// --------- MFMA GEMM: single-pass f16, 128x128 tile, 8 waves, 3x16KB counted-vmcnt ---------
// r14-verbatim config (best of 8 structural variants: 111us/GEMM). DUAL-dispatch capable:
// blockIdx.y selects param set 0 or 1 so two independent EQUAL-SIZE GEMMs share one launch
// (r16: 70.5us/GEMM co-resident vs 111 solo). r17 showed partial-size set-1 REGRESSES —
// only use dual for equal-size pairs. Set 1 nulls for single dispatches.

__global__ __launch_bounds__(512, 6) void gemm_f16_kernel(
    const ushort* __restrict__ Ahp0, const ushort* __restrict__ Wf0,
    const float* __restrict__ bias0, const float* __restrict__ amf0,
    const ushort* __restrict__ amh0, const float* __restrict__ bnst0,
    float* __restrict__ Cf0, ushort* __restrict__ Oh0, float* __restrict__ stats0,
    int relu0, int mode0,
    const ushort* __restrict__ Ahp1, const ushort* __restrict__ Wf1,
    const float* __restrict__ bias1, const float* __restrict__ amf1,
    const ushort* __restrict__ amh1, const float* __restrict__ bnst1,
    float* __restrict__ Cf1, ushort* __restrict__ Oh1, float* __restrict__ stats1,
    int relu1, int mode1,
    int M)
{
    __shared__ __align__(16) char smem[3 * 16384];   // 48KB

    // select param set (wave-uniform)
    const ushort* Ahp; const ushort* Wf; const float* bias; const float* addmat_f;
    const ushort* addmat_h; const float* bnst; float* Cf; ushort* Oh; float* stats;
    int relu, mode;
    if (blockIdx.y == 0) {
        Ahp = Ahp0; Wf = Wf0; bias = bias0; addmat_f = amf0; addmat_h = amh0;
        bnst = bnst0; Cf = Cf0; Oh = Oh0; stats = stats0; relu = relu0; mode = mode0;
    } else {
        Ahp = Ahp1; Wf = Wf1; bias = bias1; addmat_f = amf1; addmat_h = amh1;
        bnst = bnst1; Cf = Cf1; Oh = Oh1; stats = stats1; relu = relu1; mode = mode1;
    }

    int tid = threadIdx.x;
    int w = tid >> 6;       // wave 0..7
    int l = tid & 63;
    int wm = w >> 2;        // 0..1  (64-row group)
    int wn = w & 3;         // 0..3  (32-col group)

    // bijective XCD chunk swizzle, bn fastest
    int nwg = gridDim.x;
    int q = nwg >> 3, r = nwg & 7;
    int xcd = blockIdx.x & 7, idx = blockIdx.x >> 3;
    int wgid = (xcd < r ? xcd * (q + 1) : r * (q + 1) + (xcd - r) * q) + idx;
    int bm = (wgid >> 2) * 128;
    int bn = (wgid & 3) * 128;

    f32x4 acc[4][2];
#pragma unroll
    for (int i = 0; i < 4; i++)
#pragma unroll
        for (int j = 0; j < 2; j++) acc[i][j] = (f32x4){0.f, 0.f, 0.f, 0.f};

    int ro = l & 15;
    int co = l >> 4;

    size_t soff[2]; int lofs[2];
#pragma unroll
    for (int t2 = 0; t2 < 2; t2++) {
        int c = 2 * w + t2;
        int row0, base_; bool cl;
        if (c < 8) { row0 = c * 16;       base_ = bm; cl = true;  lofs[t2] = c * 1024; }
        else       { row0 = (c - 8) * 16; base_ = bn; cl = false; lofs[t2] = 8192 + (c - 8) * 1024; }
        int lrit = row0 + (l >> 2);
        int rr = base_ + lrit;
        if (cl) rr = min(rr, M - 1);
        int kc = (l & 3) ^ ((lrit >> 1) & 3);
        soff[t2] = (size_t)rr * DIM + kc * 8;
    }
    const ushort* sp0 = (2 * w < 8) ? Ahp : Wf;
    const ushort* sp1 = (2 * w + 1 < 8) ? Ahp : Wf;

    int aoff[4], woff[2];
#pragma unroll
    for (int i = 0; i < 4; i++) {
        int arow = wm * 64 + i * 16 + ro;
        aoff[i] = arow * 64 + ((co ^ ((arow >> 1) & 3)) << 4);
    }
#pragma unroll
    for (int j = 0; j < 2; j++) {
        int wrow = wn * 32 + j * 16 + ro;
        woff[j] = 8192 + wrow * 64 + ((co ^ ((wrow >> 1) & 3)) << 4);
    }

#define STAGE(BB, K0) do {                                                        \
    char* sb_ = smem + (BB) * 16384;                                              \
    gload_lds16(sp0 + soff[0] + (K0), sb_ + lofs[0]);                             \
    gload_lds16(sp1 + soff[1] + (K0), sb_ + lofs[1]);                             \
} while (0)

#define COMPUTE(BB) do {                                                          \
    const char* bb_ = (const char*)smem + (BB) * 16384;                           \
    f16x8 fa[4], fw2[2];                                                          \
    _Pragma("unroll")                                                             \
    for (int i = 0; i < 4; i++) fa[i] = *(const f16x8*)(bb_ + aoff[i]);           \
    _Pragma("unroll")                                                             \
    for (int j = 0; j < 2; j++) fw2[j] = *(const f16x8*)(bb_ + woff[j]);          \
    __builtin_amdgcn_s_setprio(1);                                                \
    _Pragma("unroll")                                                             \
    for (int i = 0; i < 4; i++)                                                   \
        _Pragma("unroll")                                                         \
        for (int j = 0; j < 2; j++)                                               \
            acc[i][j] = __builtin_amdgcn_mfma_f32_16x16x32_f16(fa[i], fw2[j], acc[i][j], 0, 0, 0); \
    __builtin_amdgcn_s_setprio(0);                                                \
} while (0)

    STAGE(0, 0);
    STAGE(1, 32);
    STAGE(2, 64);

    int bufi = 0;
    for (int ks = 0; ks < 16; ks++) {
        if (ks < 14)      { VMWAIT(4); }
        else if (ks == 14){ VMWAIT(2); }
        else              { VMWAIT(0); }
        BAR();
        COMPUTE(bufi);
        LGKM0();
        BAR();
        if (ks <= 12) STAGE(bufi, (ks + 3) * 32);
        bufi = (bufi == 2) ? 0 : bufi + 1;
    }

#undef STAGE
#undef COMPUTE

    // epilogue: C/D layout col=lane&15, row=(lane>>4)*4+reg
    int colbase = bn + wn * 32 + ro;
    int rowbase = bm + wm * 64 + co * 4;
    float sacc[2] = {0.f, 0.f};
    float qacc[2] = {0.f, 0.f};
#pragma unroll
    for (int j = 0; j < 2; j++) {
        int col = colbase + j * 16;
        float bi = bias ? bias[col] : 0.f;
        float sc = 0.f, sh = 0.f;
        if (bnst) { sc = bnst[1024 + col]; sh = bnst[1536 + col]; }
#pragma unroll
        for (int i = 0; i < 4; i++) {
#pragma unroll
            for (int rg = 0; rg < 4; rg++) {
                int row = rowbase + i * 16 + rg;
                if (row < N_NODES) {
                    float v = acc[i][j][rg] + bi;
                    if (addmat_f || addmat_h) {
                        float am = addmat_f ? addmat_f[(size_t)row * DIM + col]
                                            : h2f(addmat_h[(size_t)row * DIM + col]);
                        if (bnst) am = fmaxf(am * sc + sh, 0.f);
                        v += am;
                    }
                    if (relu) v = fmaxf(v, 0.f);
                    if (mode == 0) Cf[(size_t)row * DIM + col] = v;
                    else           Oh[(size_t)row * DIM + col] = f2h(v);
                    if (stats) { sacc[j] += v; qacc[j] += v * v; }
                }
            }
        }
    }
    if (stats) {
#pragma unroll
        for (int j = 0; j < 2; j++) {
            float ss = sacc[j], qq = qacc[j];
            ss += __shfl_xor(ss, 16); qq += __shfl_xor(qq, 16);
            ss += __shfl_xor(ss, 32); qq += __shfl_xor(qq, 32);
            if (co == 0) {
                int col = colbase + j * 16;
                atomicAdd(&stats[col], ss);
                atomicAdd(&stats[DIM + col], qq);
            }
        }
    }
}

// ---------------- batch norm finalize ----------------

__global__ void bn_finalize_kernel(float* st, const float* __restrict__ g,
                                   const float* __restrict__ b, int M) {
    int c = threadIdx.x;  // 512 threads
    float mean = st[c] / (float)M;
    float var = st[DIM + c] / (float)M - mean * mean;
    float sc = g[c] * rsqrtf(var + 1e-5f);
    st[1024 + c] = sc;
    st[1536 + c] = b[c] - mean * sc;
}

// ---------------- final pair gather + (T,512)@(512,7), f16 H ----------------

__global__ __launch_bounds__(256) void pair_kernel(const ushort* __restrict__ H,
                                                   const int* __restrict__ ei,
                                                   const int* __restrict__ teid,
                                                   const float* __restrict__ W,  // 512x7
                                                   const float* __restrict__ bias,
                                                   float* __restrict__ out) {
    int lane = threadIdx.x & 63;
    int wid = blockIdx.x * 4 + (threadIdx.x >> 6);
    int nw = gridDim.x * 4;
    int d0 = lane * 8;

    float wreg[8][NCLS];
#pragma unroll
    for (int qd = 0; qd < 8; qd++)
#pragma unroll
        for (int c = 0; c < NCLS; c++)
            wreg[qd][c] = W[(d0 + qd) * NCLS + c];
    float bi[NCLS];
#pragma unroll
    for (int c = 0; c < NCLS; c++) bi[c] = bias[c];

    for (int t = wid; t < N_TRAIN; t += nw) {
        int id = teid[t];
        int n0 = ei[id];
        int n1 = ei[N_EDGES + id];
        f16x8 av = *(const f16x8*)(H + (size_t)n0 * DIM + d0);
        f16x8 bv = *(const f16x8*)(H + (size_t)n1 * DIM + d0);
        float acc[NCLS];
#pragma unroll
        for (int c = 0; c < NCLS; c++) acc[c] = 0.f;
#pragma unroll
        for (int qd = 0; qd < 8; qd++) {
            float p = (float)av[qd] * (float)bv[qd];
#pragma unroll
            for (int c = 0; c < NCLS; c++) acc[c] += p * wreg[qd][c];
        }
#pragma unroll
        for (int off = 32; off; off >>= 1)
#pragma unroll
            for (int c = 0; c < NCLS; c++) acc[c] += __shfl_down(acc[c], off);
        if (lane == 0) {
#pragma unroll
            for (int c = 0; c < NCLS; c++) out[(size_t)t * NCLS + c] = acc[c] + bi[c];
        }
    }
}

// ---------------- launch ----------------

extern "C" void kernel_launch(void* const* d_in, const int* in_sizes, int n_in,
                              void* d_out, int out_size, void* d_ws, size_t ws_size,
                              hipStream_t stream) {
    const float* x      = (const float*)d_in[0];
    const float* graph  = (const float*)d_in[1];
    const int*   ei     = (const int*)d_in[2];
    const int*   teid   = (const int*)d_in[3];
    const float* W_sub  = (const float*)d_in[4];
    const float* bn1_g  = (const float*)d_in[5];
    const float* bn1_b  = (const float*)d_in[6];
    const float* fcx_W  = (const float*)d_in[7];
    const float* fcx_b  = (const float*)d_in[8];
    const float* eps1   = (const float*)d_in[9];
    const float* g_W1   = (const float*)d_in[10];
    const float* g_b1   = (const float*)d_in[11];
    const float* g_W2   = (const float*)d_in[12];
    const float* g_b2   = (const float*)d_in[13];
    const float* gbn_g  = (const float*)d_in[14];
    const float* gbn_b  = (const float*)d_in[15];
    const float* lin1_W = (const float*)d_in[16];
    const float* lin1_b = (const float*)d_in[17];
    const float* lin2_W = (const float*)d_in[18];
    const float* lin2_b = (const float*)d_in[19];
    const float* fc2_W  = (const float*)d_in[20];
    const float* fc2_b  = (const float*)d_in[21];
    float* out = (float*)d_out;

    char* ws = (char*)d_ws;
    size_t NB = (size_t)N_NODES * DIM * sizeof(float);    // 102.4 MB per slot
    float* slotA = (float*)(ws);
    float* slotB = (float*)(ws + NB);
    float* slotC = (float*)(ws + 2 * NB);
    float* st1   = (float*)(ws + 3 * NB);                 // 2048 floats
    float* st2   = st1 + 2048;
    int* off     = (int*)(st2 + 2048);
    int* wcur    = off + (N_NODES + 1);
    int* srclist = wcur + N_NODES;
    int* bsum    = srclist + N_EDGES;
    ushort* wt   = (ushort*)(bsum + 256);                 // 6 W^T f16, 0.5MB each
    ushort* Wsub_f = wt;
    ushort* fcx_f  = wt + 1 * 262144;
    ushort* gw1_f  = wt + 2 * 262144;
    ushort* gw2_f  = wt + 3 * 262144;
    ushort* lw2_f  = wt + 5 * 262144;
    ushort* lw1s   = wt + 6 * 262144;   // BN2-folded lin1 W^T
    float*  b1f    = (float*)(lw1s + 262144);   // BN2-folded lin1 bias (512)

    // f16 views of the fp32 slots (each slot holds two 51.2MB f16 buffers)
    size_t HN = (size_t)N_NODES * DIM;
    ushort* A_h  = (ushort*)slotA;       ushort* A2_h = A_h + HN;
    ushort* B_h  = (ushort*)slotB;       ushort* B2_h = B_h + HN;
    ushort* C2_h = (ushort*)slotC;       ushort* H_h  = C2_h + HN;

    size_t n4 = HN / 4;
    int mt = (N_NODES + 127) / 128;            // 391 row tiles
    dim3 ggrid(mt * 4);                        // 1564 blocks (single GEMM)
    dim3 gdual(mt * 4, 2);                     // dual GEMM1||GEMM2

#define GEMM1ARG(A, W, B, AF, AH, BN, CF, OH, ST, RL, MD) \
    A, W, B, AF, AH, BN, CF, OH, ST, RL, MD, \
    (const ushort*)nullptr, (const ushort*)nullptr, (const float*)nullptr, \
    (const float*)nullptr, (const ushort*)nullptr, (const float*)nullptr, \
    (float*)nullptr, (ushort*)nullptr, (float*)nullptr, 0, 0, N_NODES

    zero_kernel<<<16, 256, 0, stream>>>(st1, 4096);
    zero_kernel<<<NSB, 256, 0, stream>>>((float*)wcur, N_NODES);

    // CSR by dst
    hist_kernel<<<(N_EDGES + 255) / 256, 256, 0, stream>>>(ei, wcur);
    scan1_kernel<<<NSB, 256, 0, stream>>>(wcur, off, bsum);
    scan2_kernel<<<1, 256, 0, stream>>>(bsum);
    scan3_kernel<<<NSB, 256, 0, stream>>>(off, bsum);
    fillprep_kernel<<<NSB, 256, 0, stream>>>(off, wcur);
    fill_kernel<<<(N_EDGES + 255) / 256, 256, 0, stream>>>(ei, wcur, srclist);

    // W^T f16 conversions
    wconvert6_kernel<<<dim3(1024, 6), 256, 0, stream>>>(W_sub, fcx_W, g_W1, g_W2, lin1_W, lin2_W, wt);

    // x -> f16 A2_h (independent, early)
    convert_h_kernel<<<2048, 256, 0, stream>>>(x, A2_h, n4);
    // agg_s = graph + gather(graph) -> f16 A_h
    gather_h_kernel<<<N_NODES, 128, 0, stream>>>(graph, graph, nullptr, off, srclist, A_h);

    // DUAL: GEMM1 (y=0): sub_x_raw = A_h @ Wsub_f + graph -> f16 B_h, stats st1
    //       GEMM2 (y=1): h = A2_h @ fcx_f + fcx_b -> f16 C2_h
    gemm_f16_kernel<<<gdual, 512, 0, stream>>>(
        A_h, Wsub_f, (const float*)nullptr, graph, (const ushort*)nullptr,
        (const float*)nullptr, (float*)nullptr, B_h, st1, 0, 1,
        A2_h, fcx_f, fcx_b, (const float*)nullptr, (const ushort*)nullptr,
        (const float*)nullptr, (float*)nullptr, C2_h, (float*)nullptr, 0, 1,
        N_NODES);
    bn_finalize_kernel<<<1, 512, 0, stream>>>(st1, bn1_g, bn1_b, N_NODES);

    // agg = (1+eps)*h + gather(h) -> f16 A_h   (f16 input path)
    gather_h16_kernel<<<N_NODES, 128, 0, stream>>>(C2_h, C2_h, eps1, off, srclist, A_h);

    // GEMM3: relu(agg @ g_W1 + g_b1) -> f16 B2_h
    gemm_f16_kernel<<<ggrid, 512, 0, stream>>>(GEMM1ARG(
        A_h, gw1_f, g_b1, (const float*)nullptr, (const ushort*)nullptr,
        (const float*)nullptr, (float*)nullptr, B2_h, (float*)nullptr, 1, 1));
    // GEMM4: relu(h @ g_W2 + g_b2) -> f16 A2_h, stats st2
    gemm_f16_kernel<<<ggrid, 512, 0, stream>>>(GEMM1ARG(
        B2_h, gw2_f, g_b2, (const float*)nullptr, (const ushort*)nullptr,
        (const float*)nullptr, (float*)nullptr, A2_h, st2, 1, 1));
    bn_finalize_kernel<<<1, 512, 0, stream>>>(st2, gbn_g, gbn_b, N_NODES);

    // BN2 fold into lin1: W1' = diag(sc)W1 (f16), b1' = b1 + sh@W1
    wfold_kernel<<<1024, 256, 0, stream>>>(lin1_W, st2, lw1s);
    bfold_kernel<<<1, 512, 0, stream>>>(lin1_W, lin1_b, st2, b1f);

    // GEMM5: relu(h @ W1' + b1') -> f16 A_h
    gemm_f16_kernel<<<ggrid, 512, 0, stream>>>(GEMM1ARG(
        A2_h, lw1s, b1f, (const float*)nullptr, (const ushort*)nullptr,
        (const float*)nullptr, (float*)nullptr, A_h, (float*)nullptr, 1, 1));
    // GEMM6: H = h @ lin2_W + lin2_b + relu(bn1(sub_x_raw)) -> f16 H_h
    gemm_f16_kernel<<<ggrid, 512, 0, stream>>>(GEMM1ARG(
        A_h, lw2_f, lin2_b, (const float*)nullptr, B_h,
        st1, (float*)nullptr, H_h, (float*)nullptr, 0, 1));

    // out = (H[n0]*H[n1]) @ fc2_W + fc2_b   (f16 H)
    pair_kernel<<<2048, 256, 0, stream>>>(H_h, ei, teid, fc2_W, fc2_b, out);

#undef GEMM1ARG
}